// Round 3
// baseline (104.876 us; speedup 1.0000x reference)
//
#include <hip/hip_runtime.h>

// Sinkhorn via separable kernel: K = exp(-C/eps) = G (x) G (kron), with
// G[a][b] = exp(-100 * C1d[a][b]) read as exact 1D slices of the provided C
// (preserves reference's rounded dy^2). K.x = y-conv(G, x-conv(G, x)).
// Cost pass: K o C = H(x)G + G(x)H with H = G * C1d.
// One block per batch (32 blocks), whole chain in one kernel, state in LDS.
// This round: intermediate stored TRANSPOSED so both conv steps read LDS
// row-wise as float4 (ds_read_b128, 12 insts/wave/step vs 48 scalar);
// LD=52 keeps rows 16B-aligned, column writes lane-contiguous (no conflict);
// packed fp32 FMA (v_pk_fma_f32) halves VALU issue; G/H read wave-uniform
// float4 -> s_load_dwordx4 (scalar pipe). 12 waves x 4 rows.

#define SZ 48
#define SN 2304          // 48*48
#define LD 52            // padded LDS row stride (52*4 = 208 B, 16B-aligned)
#define NBAT 32
#define NTHR 768         // 12 waves
#define NW 12
#define YB 4             // output rows per wave (12*4 = 48)

typedef float f2 __attribute__((ext_vector_type(2)));

__device__ __forceinline__ f2 pkfma(f2 a, f2 b, f2 c) {
#if __has_builtin(__builtin_elementwise_fma)
    return __builtin_elementwise_fma(a, b, c);
#else
    f2 r; r.x = fmaf(a.x, b.x, c.x); r.y = fmaf(a.y, b.y, c.y); return r;
#endif
}

__global__ __launch_bounds__(256) void k_pre(const float* __restrict__ C,
                                             float* __restrict__ G,
                                             float* __restrict__ H) {
    const int idx = blockIdx.x * 256 + threadIdx.x;   // 9*256 = 2304 exactly
    const int a = idx / SZ;
    const int c = idx - a * SZ;
    const float cv = C[(size_t)a * SZ * SN + (size_t)c * SZ];
    const float g = expf(-100.f * cv);
    G[idx] = g;
    H[idx] = g * cv;
}

// conv body: given per-lane row pointer `row` (16B-aligned, 48 floats),
// accumulate a0 = {r0+0,r0+1}, a1 = {r0+2,r0+3} of sum_j M[j][r0+k]*row[j].
#define CONV_STEP(row, Mm, a0, a1)                                          \
    {                                                                       \
        _Pragma("unroll")                                                   \
        for (int jc = 0; jc < 12; ++jc) {                                   \
            const float4 q = *(const float4*)&(row)[jc * 4];                \
            _Pragma("unroll")                                               \
            for (int jj = 0; jj < 4; ++jj) {                                \
                const int j = jc * 4 + jj;                                  \
                const float4 g = *(const float4*)((Mm) + j * SZ + r0);      \
                const float v = (jj == 0) ? q.x : (jj == 1) ? q.y           \
                              : (jj == 2) ? q.z : q.w;                      \
                const f2 vv = {v, v};                                       \
                a0 = pkfma((f2){g.x, g.y}, vv, a0);                         \
                a1 = pkfma((f2){g.z, g.w}, vv, a1);                         \
            }                                                               \
        }                                                                   \
    }

__global__ __launch_bounds__(NTHR) void k_sink(const float* __restrict__ pred,
                                               const float* __restrict__ tgt,
                                               const float* __restrict__ Gm,
                                               const float* __restrict__ Hm,
                                               float* __restrict__ out) {
    __shared__ float Fa[SZ * LD];    // alpha scaling
    __shared__ float Fb[SZ * LD];    // beta scaling (init 1)
    __shared__ float Fms[SZ * LD];   // mass_source; reused as T2t in final
    __shared__ float Fmt[SZ * LD];   // mass_target
    __shared__ float Tt[SZ * LD];    // conv intermediate, TRANSPOSED [xi][y]
    __shared__ float gsl[SZ];        // row sums of G (folded pass 0)
    __shared__ float red[32];

    const int t = threadIdx.x;
    const int b = blockIdx.x;
    const int l = t & 63;
    const int w = __builtin_amdgcn_readfirstlane(t >> 6);  // scalar wave id
    const int r0 = w * YB;                                 // wave's output rows

    // ---- init: G row sums, load channel-0 planes, sum, normalize ----
    if (t < SZ) {
        float s = 0.f;
        #pragma unroll 8
        for (int j = 0; j < SZ; ++j) s += Gm[t * SZ + j];
        gsl[t] = s;
    }
    const float* __restrict__ pg = pred + (size_t)b * 3 * SN;
    const float* __restrict__ tg = tgt + (size_t)b * 3 * SN;
    float sp = 0.f, st = 0.f;
    for (int i = t; i < SN; i += NTHR) {
        const float vp = pg[i] + 1e-9f;
        const float vt = tg[i] + 1e-9f;
        const int y = i / SZ, x = i - y * SZ;
        Fms[y * LD + x] = vp;
        Fmt[y * LD + x] = vt;
        sp += vp; st += vt;
    }
    #pragma unroll
    for (int off = 32; off; off >>= 1) {
        sp += __shfl_down(sp, off);
        st += __shfl_down(st, off);
    }
    if (l == 0) { red[w] = sp; red[16 + w] = st; }
    __syncthreads();
    float ps = 0.f, ts = 0.f;
    #pragma unroll
    for (int k = 0; k < NW; ++k) { ps += red[k]; ts += red[16 + k]; }
    // folded pass 0: Fa = m_src / (gs[y]*gs[x] + 1e-6), Fb = 1
    for (int i = t; i < SN; i += NTHR) {
        const int y = i / SZ, x = i - y * SZ;
        const float ms = Fms[y * LD + x] / ps;
        Fms[y * LD + x] = ms;
        Fmt[y * LD + x] /= ts;
        Fa[y * LD + x] = ms / (gsl[y] * gsl[x] + 1e-6f);
        Fb[y * LD + x] = 1.f;
    }
    __syncthreads();

    // ---- remaining 9 half-iterations (p=1..9) ----
    for (int p = 1; p < 10; ++p) {
        float* __restrict__ src = (p & 1) ? Fa : Fb;
        float* __restrict__ dst = (p & 1) ? Fb : Fa;
        const float* __restrict__ mv = (p & 1) ? Fmt : Fms;

        // step1 (x-conv): Tt[xi][y] = sum_j G[xi][j] * src[y][j]
        // lane l = y reads its row as float4; writes transposed (lane-contig)
        if (l < SZ) {
            f2 a0 = {0.f, 0.f}, a1 = {0.f, 0.f};
            CONV_STEP(&src[l * LD], Gm, a0, a1);
            Tt[(r0 + 0) * LD + l] = a0.x;
            Tt[(r0 + 1) * LD + l] = a0.y;
            Tt[(r0 + 2) * LD + l] = a1.x;
            Tt[(r0 + 3) * LD + l] = a1.y;
        }
        __syncthreads();

        // step2 (y-conv) + fused update: S[yi][x] = sum_j G[yi][j]*Tt[x][j]
        // lane l = x reads Tt row as float4 (Tt[x][j] = T[j][x])
        if (l < SZ) {
            f2 a0 = {0.f, 0.f}, a1 = {0.f, 0.f};
            CONV_STEP(&Tt[l * LD], Gm, a0, a1);
            const float s4[4] = {a0.x, a0.y, a1.x, a1.y};
            #pragma unroll
            for (int k = 0; k < YB; ++k) {
                const int idx = (r0 + k) * LD + l;
                const float yo = dst[idx];
                dst[idx] = mv[idx] * yo / (yo * s4[k] + 1e-6f);
            }
        }
        __syncthreads();
    }

    // ---- final: cost = sum Fa .* ((H(x)G + G(x)H) applied to Fb) ----
    // stage 1: T1t = (G-x-conv(beta))^T in Tt, T2t = (H-x-conv(beta))^T in Fms
    if (l < SZ) {
        f2 t1a = {0.f, 0.f}, t1b = {0.f, 0.f};
        f2 t2a = {0.f, 0.f}, t2b = {0.f, 0.f};
        #pragma unroll
        for (int jc = 0; jc < 12; ++jc) {
            const float4 q = *(const float4*)&Fb[l * LD + jc * 4];
            #pragma unroll
            for (int jj = 0; jj < 4; ++jj) {
                const int j = jc * 4 + jj;
                const float4 g = *(const float4*)(Gm + j * SZ + r0);
                const float4 h = *(const float4*)(Hm + j * SZ + r0);
                const float v = (jj == 0) ? q.x : (jj == 1) ? q.y
                              : (jj == 2) ? q.z : q.w;
                const f2 vv = {v, v};
                t1a = pkfma((f2){g.x, g.y}, vv, t1a);
                t1b = pkfma((f2){g.z, g.w}, vv, t1b);
                t2a = pkfma((f2){h.x, h.y}, vv, t2a);
                t2b = pkfma((f2){h.z, h.w}, vv, t2b);
            }
        }
        Tt [(r0 + 0) * LD + l] = t1a.x;  Tt [(r0 + 1) * LD + l] = t1a.y;
        Tt [(r0 + 2) * LD + l] = t1b.x;  Tt [(r0 + 3) * LD + l] = t1b.y;
        Fms[(r0 + 0) * LD + l] = t2a.x;  Fms[(r0 + 1) * LD + l] = t2a.y;
        Fms[(r0 + 2) * LD + l] = t2b.x;  Fms[(r0 + 3) * LD + l] = t2b.y;
    }
    __syncthreads();

    // stage 2: U[yi][x] = sum_j H[yi][j]*T1t[x][j] + G[yi][j]*T2t[x][j]
    float part = 0.f;
    if (l < SZ) {
        f2 u0 = {0.f, 0.f}, u1 = {0.f, 0.f};
        #pragma unroll
        for (int jc = 0; jc < 12; ++jc) {
            const float4 q1 = *(const float4*)&Tt [l * LD + jc * 4];
            const float4 q2 = *(const float4*)&Fms[l * LD + jc * 4];
            #pragma unroll
            for (int jj = 0; jj < 4; ++jj) {
                const int j = jc * 4 + jj;
                const float4 g = *(const float4*)(Gm + j * SZ + r0);
                const float4 h = *(const float4*)(Hm + j * SZ + r0);
                const float v1 = (jj == 0) ? q1.x : (jj == 1) ? q1.y
                               : (jj == 2) ? q1.z : q1.w;
                const float v2 = (jj == 0) ? q2.x : (jj == 1) ? q2.y
                               : (jj == 2) ? q2.z : q2.w;
                const f2 vv1 = {v1, v1};
                const f2 vv2 = {v2, v2};
                u0 = pkfma((f2){h.x, h.y}, vv1, u0);
                u1 = pkfma((f2){h.z, h.w}, vv1, u1);
                u0 = pkfma((f2){g.x, g.y}, vv2, u0);
                u1 = pkfma((f2){g.z, g.w}, vv2, u1);
            }
        }
        const float u4[4] = {u0.x, u0.y, u1.x, u1.y};
        #pragma unroll
        for (int k = 0; k < YB; ++k)
            part = fmaf(Fa[(r0 + k) * LD + l], u4[k], part);
    }
    #pragma unroll
    for (int off = 32; off; off >>= 1) part += __shfl_down(part, off);
    if (l == 0) red[w] = part;
    __syncthreads();
    if (t == 0) {
        float c = 0.f;
        #pragma unroll
        for (int k = 0; k < NW; ++k) c += red[k];
        out[b] = c;
    }
}

extern "C" void kernel_launch(void* const* d_in, const int* in_sizes, int n_in,
                              void* d_out, int out_size, void* d_ws, size_t ws_size,
                              hipStream_t stream) {
    const float* pred = (const float*)d_in[0];
    const float* tgt  = (const float*)d_in[1];
    const float* C    = (const float*)d_in[2];
    float* G = (float*)d_ws;          // 2304 floats
    float* H = G + SN;                // 2304 floats

    k_pre<<<9, 256, 0, stream>>>(C, G, H);
    k_sink<<<NBAT, NTHR, 0, stream>>>(pred, tgt, G, H, (float*)d_out);
}